// Round 18
// baseline (271.788 us; speedup 1.0000x reference)
//
#include <hip/hip_runtime.h>
#include <math.h>

#define S_LEN 2048
#define D_MODEL 1024
#define NHEAD 16
#define HDIM 64
#define DFF 4096
#define IH 4
#define IDM 64
#define TOPK 64
#define NIDX 336   // 256 qi + 64 ki + 4 wi + 12 pad

typedef float f32x4 __attribute__((ext_vector_type(4)));
typedef short bf16x8 __attribute__((ext_vector_type(8)));

__device__ __forceinline__ unsigned short f2bf(float f) {
    unsigned u = __builtin_bit_cast(unsigned, f);
    u += 0x7fff + ((u >> 16) & 1);
    return (unsigned short)(u >> 16);
}
__device__ __forceinline__ float bf2f(unsigned short us) {
    return __builtin_bit_cast(float, (unsigned)us << 16);
}

__device__ __forceinline__ float gelu_exact(float v) {
    return 0.5f * v * (1.f + erff(v * 0.70710678118654752f));
}

__device__ __forceinline__ void gl_lds16(const void* g, void* l) {
    __builtin_amdgcn_global_load_lds(
        (const __attribute__((address_space(1))) void*)g,
        (__attribute__((address_space(3))) void*)l, 16, 0, 0);
}

// ---------------- Fused w_o split-K reduce + residual + LN2 ----------------
__global__ __launch_bounds__(256) void wo_ln2_kernel(const float* __restrict__ Pwo,
    const float* __restrict__ x, const float* __restrict__ g, const float* __restrict__ b,
    float* __restrict__ outf, unsigned short* __restrict__ outb)
{
    int row = blockIdx.x, tid = threadIdx.x;
    size_t MN = (size_t)S_LEN * D_MODEL;
    size_t off = (size_t)row * D_MODEL + tid * 4;
    float4 p0 = *(const float4*)(Pwo + off);
    float4 p1 = *(const float4*)(Pwo + MN + off);
    float4 xr = *(const float4*)(x + off);
    float4 v;
    v.x = p0.x + p1.x + xr.x;
    v.y = p0.y + p1.y + xr.y;
    v.z = p0.z + p1.z + xr.z;
    v.w = p0.w + p1.w + xr.w;
    *(float4*)(outf + off) = v;
    float s = v.x + v.y + v.z + v.w;
    float ss = v.x * v.x + v.y * v.y + v.z * v.z + v.w * v.w;
    int lane = tid & 63, wv = tid >> 6;
    for (int o = 32; o; o >>= 1) { s += __shfl_xor(s, o); ss += __shfl_xor(ss, o); }
    __shared__ float rs[4], rss[4];
    if (lane == 0) { rs[wv] = s; rss[wv] = ss; }
    __syncthreads();
    float S = rs[0] + rs[1] + rs[2] + rs[3];
    float SS = rss[0] + rss[1] + rss[2] + rss[3];
    float mean = S * (1.f / D_MODEL);
    float var = SS * (1.f / D_MODEL) - mean * mean;
    float r = rsqrtf(var + 1e-5f);
    float4 gv = *(const float4*)(g + tid * 4);
    float4 bv = *(const float4*)(b + tid * 4);
    ushort4 u4 = { f2bf((v.x - mean) * r * gv.x + bv.x),
                   f2bf((v.y - mean) * r * gv.y + bv.y),
                   f2bf((v.z - mean) * r * gv.z + bv.z),
                   f2bf((v.w - mean) * r * gv.w + bv.w) };
    *(ushort4*)(outb + off) = u4;
}

// ---------------- wtrans body: fp32 [K][N] -> bf16 [N][K], one 32x32 tile ----------------
__device__ __forceinline__ void wtrans_body(const float* __restrict__ in,
    unsigned short* __restrict__ out, int K, int N, int bx, int by, int tid)
{
    __shared__ float t[32][33];
    int k0 = by * 32, n0 = bx * 32;
    int r = tid >> 5, c = tid & 31;
#pragma unroll
    for (int p = 0; p < 4; ++p)
        t[r + p * 8][c] = in[(size_t)(k0 + r + p * 8) * N + n0 + c];
    __syncthreads();
#pragma unroll
    for (int p = 0; p < 4; ++p)
        out[(size_t)(n0 + r + p * 8) * K + k0 + c] = f2bf(t[c][r + p * 8]);
}

// ---------------- Fused prep: LN1 + rope tables + 4x weight transpose + indexer pack ----------------
#define PREP_LN1    2048
#define PREP_ROPE   256
#define PREP_WQKV   3072
#define PREP_WO     1024
#define PREP_W1     4096
#define PREP_W2     4096
#define PREP_WPACK  1344
#define PREP_TOTAL  (PREP_LN1 + PREP_ROPE + PREP_WQKV + PREP_WO + PREP_W1 + PREP_W2 + PREP_WPACK)
__global__ __launch_bounds__(256) void prep_kernel(
    const float* __restrict__ x, const float* __restrict__ ln1_g, const float* __restrict__ ln1_b,
    const float* __restrict__ w_qkv, const float* __restrict__ w_o,
    const float* __restrict__ w1, const float* __restrict__ w2,
    const float* __restrict__ wq, const float* __restrict__ wk, const float* __restrict__ ww,
    float* __restrict__ normx, unsigned short* __restrict__ normx_bf,
    unsigned short* __restrict__ wqkv_t, unsigned short* __restrict__ wo_t,
    unsigned short* __restrict__ w1_t, unsigned short* __restrict__ w2_t,
    float* __restrict__ Wc, float* __restrict__ ct, float* __restrict__ st)
{
    int b = blockIdx.x, tid = threadIdx.x;
    if (b < PREP_LN1) {
        int row = b;
        const float4 v = *(const float4*)(x + (size_t)row * D_MODEL + tid * 4);
        float s = v.x + v.y + v.z + v.w;
        float ss = v.x * v.x + v.y * v.y + v.z * v.z + v.w * v.w;
        int lane = tid & 63, wv = tid >> 6;
        for (int o = 32; o; o >>= 1) { s += __shfl_xor(s, o); ss += __shfl_xor(ss, o); }
        __shared__ float rs[4], rss[4];
        if (lane == 0) { rs[wv] = s; rss[wv] = ss; }
        __syncthreads();
        float S = rs[0] + rs[1] + rs[2] + rs[3];
        float SS = rss[0] + rss[1] + rss[2] + rss[3];
        float mean = S * (1.f / D_MODEL);
        float var = SS * (1.f / D_MODEL) - mean * mean;
        float r = rsqrtf(var + 1e-5f);
        float4 gv = *(const float4*)(ln1_g + tid * 4);
        float4 bv = *(const float4*)(ln1_b + tid * 4);
        float4 o4;
        o4.x = (v.x - mean) * r * gv.x + bv.x;
        o4.y = (v.y - mean) * r * gv.y + bv.y;
        o4.z = (v.z - mean) * r * gv.z + bv.z;
        o4.w = (v.w - mean) * r * gv.w + bv.w;
        *(float4*)(normx + (size_t)row * D_MODEL + tid * 4) = o4;
        ushort4 u4 = { f2bf(o4.x), f2bf(o4.y), f2bf(o4.z), f2bf(o4.w) };
        *(ushort4*)(normx_bf + (size_t)row * D_MODEL + tid * 4) = u4;
        return;
    }
    b -= PREP_LN1;
    if (b < PREP_ROPE) {
        int g = b * 256 + tid;
        int t = g >> 5, i = g & 31;
        float theta = powf(10000.f, -(float)i / 32.f);
        float ang = (float)t * theta;
        ct[g] = cosf(ang);
        st[g] = sinf(ang);
        return;
    }
    b -= PREP_ROPE;
    if (b < PREP_WQKV) { wtrans_body(w_qkv, wqkv_t, 1024, 3072, b % 96, b / 96, tid); return; }
    b -= PREP_WQKV;
    if (b < PREP_WO)   { wtrans_body(w_o, wo_t, 1024, 1024, b % 32, b / 32, tid); return; }
    b -= PREP_WO;
    if (b < PREP_W1)   { wtrans_body(w1, w1_t, 1024, 4096, b % 128, b / 128, tid); return; }
    b -= PREP_W1;
    if (b < PREP_W2)   { wtrans_body(w2, w2_t, 4096, 1024, b % 32, b / 32, tid); return; }
    b -= PREP_W2;
    {
        int idx = b * 256 + tid;
        if (idx >= D_MODEL * NIDX) return;
        int r = idx / NIDX, c = idx % NIDX;
        float v = 0.f;
        if (c < 256) v = wq[r * 256 + c];
        else if (c < 320) v = wk[r * 64 + (c - 256)];
        else if (c < 324) v = ww[r * 4 + (c - 320)];
        Wc[idx] = v;
    }
}

// ---------------- bf16 MFMA GEMM, 128x64 tile: A->regs (issued FIRST), B-only LDS pipeline ----------------
// Fix of the r13 ordering bug: A(t+1) register loads are issued BEFORE STAGE_B(t+2), so the
// implicit wait for A regs (vmcnt(1)) leaves only B(t+2) in flight; explicit vmcnt(1) before
// the barrier proves B(t+1) landed. LDS ops/wave-step drop 9 -> 5; LDS 36KB -> 12KB.
__global__ __launch_bounds__(256) void gemm_bf16_n64(
    const unsigned short* __restrict__ A, const unsigned short* __restrict__ Bt,
    float* __restrict__ C, unsigned short* __restrict__ Cb,
    const float* __restrict__ bias, const float* __restrict__ R,
    int M, int N, int K, int act,
    float* __restrict__ P, int kchunk)
{
    __shared__ __attribute__((aligned(16))) unsigned short Bs[3][64 * 32];
    int tid = threadIdx.x;
    int bm = blockIdx.y * 128, bn = blockIdx.x * 64;
    int wid = tid >> 6, lane = tid & 63;
    int wm = wid * 32;
    const unsigned short* Ab = A + (size_t)bm * K;
    const unsigned short* Bb = Bt + (size_t)bn * K;
    f32x4 acc[2][4];
#pragma unroll
    for (int i = 0; i < 2; ++i)
#pragma unroll
        for (int j = 0; j < 4; ++j)
            acc[i][j] = (f32x4){0.f, 0.f, 0.f, 0.f};

    int kbeg = blockIdx.z * kchunk;
    int NT = kchunk >> 5;
    int fr = lane & 15, fk = (lane >> 4) * 8;
    int e0 = tid * 8;                 // B staging: 2048 elems over 256 lanes
    int r0 = e0 >> 5, c0 = e0 & 31;
    const unsigned short* Ar0 = Ab + (size_t)(wm + fr) * K + fk;
    const unsigned short* Ar1 = Ab + (size_t)(wm + 16 + fr) * K + fk;

    auto STAGE_B = [&](int kt, int buf) {
        gl_lds16(Bb + (size_t)r0 * K + kbeg + kt * 32 + c0, &Bs[buf][e0]);
    };
    auto COMPUTE = [&](int buf, bf16x8 a0, bf16x8 a1) {
        bf16x8 bfv[4];
#pragma unroll
        for (int ni = 0; ni < 4; ++ni)
            bfv[ni] = *(const bf16x8*)&Bs[buf][(ni * 16 + fr) * 32 + fk];
#pragma unroll
        for (int ni = 0; ni < 4; ++ni) {
            acc[0][ni] = __builtin_amdgcn_mfma_f32_16x16x32_bf16(a0, bfv[ni], acc[0][ni], 0, 0, 0);
            acc[1][ni] = __builtin_amdgcn_mfma_f32_16x16x32_bf16(a1, bfv[ni], acc[1][ni], 0, 0, 0);
        }
    };

    // prologue: A(0) regs first, then B(0), B(1)
    bf16x8 a0 = *(const bf16x8*)(Ar0 + kbeg);
    bf16x8 a1 = *(const bf16x8*)(Ar1 + kbeg);
    STAGE_B(0, 0);
    STAGE_B(1, 1);
    asm volatile("s_waitcnt vmcnt(1)" ::: "memory");   // a0,a1,B(0) landed; B(1) in flight
    __builtin_amdgcn_s_barrier();

    for (int kt = 0; kt < NT - 2; ++kt) {
        int kn = kbeg + (kt + 1) * 32;
        bf16x8 an0 = *(const bf16x8*)(Ar0 + kn);      // A(t+1) issued FIRST
        bf16x8 an1 = *(const bf16x8*)(Ar1 + kn);
        STAGE_B(kt + 2, (kt + 2) % 3);                // then B(t+2)
        COMPUTE(kt % 3, a0, a1);
        a0 = an0; a1 = an1;                           // implicit wait leaves only B(t+2)
        asm volatile("s_waitcnt vmcnt(1)" ::: "memory");  // B(t+1)+A(t+1) landed
        __builtin_amdgcn_s_barrier();
    }
    {   // kt = NT-2: no more B to stage
        int kn = kbeg + (NT - 1) * 32;
        bf16x8 an0 = *(const bf16x8*)(Ar0 + kn);
        bf16x8 an1 = *(const bf16x8*)(Ar1 + kn);
        COMPUTE((NT - 2) % 3, a0, a1);
        a0 = an0; a1 = an1;
        asm volatile("s_waitcnt vmcnt(0)" ::: "memory");
        __builtin_amdgcn_s_barrier();
        COMPUTE((NT - 1) % 3, a0, a1);
    }

    int cl = lane & 15, rh = (lane >> 4) * 4;
    if (P) {
        float* Pz = P + (size_t)blockIdx.z * M * N;
#pragma unroll
        for (int mi = 0; mi < 2; ++mi)
#pragma unroll
            for (int ni = 0; ni < 4; ++ni) {
                int col = bn + ni * 16 + cl;
#pragma unroll
                for (int r = 0; r < 4; ++r) {
                    int row = bm + wm + mi * 16 + rh + r;
                    Pz[(size_t)row * N + col] = acc[mi][ni][r];
                }
            }
        return;
    }
#pragma unroll
    for (int mi = 0; mi < 2; ++mi) {
#pragma unroll
        for (int ni = 0; ni < 4; ++ni) {
            int col = bn + ni * 16 + cl;
            float bv = bias ? bias[col] : 0.f;
#pragma unroll
            for (int r = 0; r < 4; ++r) {
                int row = bm + wm + mi * 16 + rh + r;
                float v = acc[mi][ni][r] + bv;
                if (act) v = gelu_exact(v);
                size_t off = (size_t)row * N + col;
                if (R) v += R[off];
                if (C) C[off] = v;
                if (Cb) Cb[off] = f2bf(v);
            }
        }
    }
}

// ---------------- qkv GEMM + fused RoPE + pack (unchanged control: all-LDS pipeline) ----------------
__global__ __launch_bounds__(256) void gemm_qkv_rope(
    const unsigned short* __restrict__ A, const unsigned short* __restrict__ Bt,
    const float* __restrict__ ct, const float* __restrict__ st,
    unsigned short* __restrict__ Qb, unsigned short* __restrict__ Kb,
    unsigned short* __restrict__ Vb)
{
    const int K = D_MODEL, NT = D_MODEL / 32;
    __shared__ __attribute__((aligned(16))) unsigned short As[3][128 * 32];
    __shared__ __attribute__((aligned(16))) unsigned short Bs[3][64 * 32];
    int tid = threadIdx.x;
    int bm = blockIdx.y * 128, bn = blockIdx.x * 64;
    int wid = tid >> 6, lane = tid & 63;
    int wm = wid * 32;
    const unsigned short* Ab = A + (size_t)bm * K;
    const unsigned short* Bb = Bt + (size_t)bn * K;
    f32x4 acc[2][4];
#pragma unroll
    for (int i = 0; i < 2; ++i)
#pragma unroll
        for (int j = 0; j < 4; ++j)
            acc[i][j] = (f32x4){0.f, 0.f, 0.f, 0.f};

    int fr = lane & 15, fk = (lane >> 4) * 8;
    int e0 = tid * 8;
    int r0 = e0 >> 5, c0 = e0 & 31;

    auto STAGE = [&](int kt, int buf) {
        int k0 = kt * 32;
        gl_lds16(Ab + (size_t)r0 * K + k0 + c0, &As[buf][e0]);
        gl_lds16(Ab + (size_t)(r0 + 64) * K + k0 + c0, &As[buf][e0 + 2048]);
        gl_lds16(Bb + (size_t)r0 * K + k0 + c0, &Bs[buf][e0]);
    };
    auto COMPUTE = [&](int buf) {
        bf16x8 af[2], bfv[4];
#pragma unroll
        for (int mi = 0; mi < 2; ++mi)
            af[mi] = *(const bf16x8*)&As[buf][(wm + mi * 16 + fr) * 32 + fk];
#pragma unroll
        for (int ni = 0; ni < 4; ++ni)
            bfv[ni] = *(const bf16x8*)&Bs[buf][(ni * 16 + fr) * 32 + fk];
#pragma unroll
        for (int mi = 0; mi < 2; ++mi)
#pragma unroll
            for (int ni = 0; ni < 4; ++ni)
                acc[mi][ni] = __builtin_amdgcn_mfma_f32_16x16x32_bf16(
                    af[mi], bfv[ni], acc[mi][ni], 0, 0, 0);
    };

    STAGE(0, 0);
    STAGE(1, 1);
    asm volatile("s_waitcnt vmcnt(3)" ::: "memory");
    __builtin_amdgcn_s_barrier();
    for (int kt = 0; kt < NT - 2; ++kt) {
        STAGE(kt + 2, (kt + 2) % 3);
        COMPUTE(kt % 3);
        asm volatile("s_waitcnt vmcnt(3)" ::: "memory");
        __builtin_amdgcn_s_barrier();
    }
    COMPUTE((NT - 2) % 3);
    asm volatile("s_waitcnt vmcnt(0)" ::: "memory");
    __builtin_amdgcn_s_barrier();
    COMPUTE((NT - 1) % 3);

    int cl = lane & 15, rh = (lane >> 4) * 4;
    int region = bn >> 10;            // 0=Q, 1=K, 2=V
    int hh = (bn & 1023) >> 6;        // head
    if (region == 2) {
#pragma unroll
        for (int mi = 0; mi < 2; ++mi)
#pragma unroll
            for (int ni = 0; ni < 4; ++ni) {
                int d = ni * 16 + cl;
#pragma unroll
                for (int r = 0; r < 4; ++r) {
                    int row = bm + wm + mi * 16 + rh + r;
                    Vb[((size_t)hh * S_LEN + row) * HDIM + d] = f2bf(acc[mi][ni][r]);
                }
            }
    } else {
#pragma unroll
        for (int mi = 0; mi < 2; ++mi)
#pragma unroll
            for (int ni = 0; ni < 4; ++ni) {
                int d = ni * 16 + cl;
                int i = d >> 1;
                bool odd = d & 1;
#pragma unroll
                for (int r = 0; r < 4; ++r) {
                    int row = bm + wm + mi * 16 + rh + r;
                    float v = acc[mi][ni][r];
                    float p = __shfl_xor(v, 1);
                    float c = ct[row * 32 + i], s = st[row * 32 + i];
                    float o = odd ? (v * c + p * s) : (v * c - p * s);
                    if (region == 0)
                        Qb[(size_t)row * D_MODEL + bn + d] = f2bf(o);
                    else
                        Kb[((size_t)hh * S_LEN + row) * HDIM + d] = f2bf(o);
                }
            }
    }
}

// ---------------- Split-K reduce: C = sum_z P[z] + bias + R (float4 vectorized) ----------------
__global__ __launch_bounds__(256) void kreduce_kernel(const float* __restrict__ P,
    int nslice, float* __restrict__ C, const float* __restrict__ bias,
    const float* __restrict__ R, int M, int N)
{
    size_t total4 = (size_t)M * N / 4;
    size_t stride = (size_t)gridDim.x * 256;
    for (size_t i4 = blockIdx.x * 256 + threadIdx.x; i4 < total4; i4 += stride) {
        size_t off = i4 * 4;
        float4 v = *(const float4*)(P + off);
        for (int z = 1; z < nslice; ++z) {
            float4 p = *(const float4*)(P + (size_t)z * M * N + off);
            v.x += p.x; v.y += p.y; v.z += p.z; v.w += p.w;
        }
        if (bias) {
            float4 b4 = *(const float4*)(bias + (off % N));
            v.x += b4.x; v.y += b4.y; v.z += b4.z; v.w += b4.w;
        }
        if (R) {
            float4 r4 = *(const float4*)(R + off);
            v.x += r4.x; v.y += r4.y; v.z += r4.z; v.w += r4.w;
        }
        *(float4*)(C + off) = v;
    }
}

// ---------------- Generic fp32 GEMM (indexer path): C[M,N] = A[M,K]@B[K,N] ----------------
__global__ __launch_bounds__(256) void gemm64(const float* __restrict__ A,
    const float* __restrict__ B, float* __restrict__ C,
    int M, int N, int K,
    float* __restrict__ P, int kchunk)
{
    __shared__ float As[16][68];
    __shared__ float Bs[16][68];
    int tid = threadIdx.x;
    int bm = blockIdx.y, bn = blockIdx.x;
    int tx = tid & 15, ty = tid >> 4;
    int arow = tid >> 2;
    int acol = (tid & 3) << 2;
    int brow = tid >> 4;
    int bcol = (tid & 15) << 2;
    const float* Abase = A + (size_t)(bm * 64 + arow) * K + acol;
    float c[4][4] = {};
    int kbeg = blockIdx.z * kchunk;
    int kend = kbeg + kchunk;
    for (int k0 = kbeg; k0 < kend; k0 += 16) {
        float4 av = *(const float4*)(Abase + k0);
        As[acol + 0][arow] = av.x;
        As[acol + 1][arow] = av.y;
        As[acol + 2][arow] = av.z;
        As[acol + 3][arow] = av.w;
        int gcol = bn * 64 + bcol;
        const float* Bb = B + (size_t)(k0 + brow) * N;
        float4 bv;
        if (gcol + 3 < N) {
            bv = *(const float4*)(Bb + gcol);
        } else {
            bv.x = (gcol + 0 < N) ? Bb[gcol + 0] : 0.f;
            bv.y = (gcol + 1 < N) ? Bb[gcol + 1] : 0.f;
            bv.z = (gcol + 2 < N) ? Bb[gcol + 2] : 0.f;
            bv.w = (gcol + 3 < N) ? Bb[gcol + 3] : 0.f;
        }
        *(float4*)&Bs[brow][bcol] = bv;
        __syncthreads();
#pragma unroll
        for (int kk = 0; kk < 16; ++kk) {
            float4 a4 = *(const float4*)&As[kk][ty * 4];
            float4 b4 = *(const float4*)&Bs[kk][tx * 4];
            float av4[4] = { a4.x, a4.y, a4.z, a4.w };
            float bv4[4] = { b4.x, b4.y, b4.z, b4.w };
#pragma unroll
            for (int i = 0; i < 4; ++i)
#pragma unroll
                for (int j = 0; j < 4; ++j)
                    c[i][j] += av4[i] * bv4[j];
        }
        __syncthreads();
    }
    float* Out = P ? (P + (size_t)blockIdx.z * M * N) : C;
#pragma unroll
    for (int i = 0; i < 4; ++i) {
        int row = bm * 64 + ty * 4 + i;
#pragma unroll
        for (int j = 0; j < 4; ++j) {
            int col = bn * 64 + tx * 4 + j;
            if (col < N)
                Out[(size_t)row * N + col] = c[i][j];
        }
    }
}

// ---------------- Indexer scores v2: 64x64 tile, d-major LDS, 4x4 register blocking ----------------
__global__ __launch_bounds__(256) void scores_kernel(const float* __restrict__ QIW,
    float* __restrict__ scores)
{
    int t0 = blockIdx.y * 64, s0 = blockIdx.x * 64;
    if (s0 > t0 + 63) return;
    __shared__ float qit[64][68];   // [d][t]
    __shared__ float kit[64][68];   // [d][s]
    __shared__ float wis[64][4];
    int tid = threadIdx.x;
    int tx = tid & 15, ty = tid >> 4;
    int lr = tid & 63;
    int cseg = tid >> 6;
    if (tid < 64) {
        float4 w4 = *(const float4*)(QIW + (size_t)(t0 + tid) * NIDX + 320);
        wis[tid][0] = w4.x; wis[tid][1] = w4.y; wis[tid][2] = w4.z; wis[tid][3] = w4.w;
    }
    float acc[4][4] = {};
#pragma unroll
    for (int h = 0; h < 4; ++h) {
        __syncthreads();
        const float* qrow = QIW + (size_t)(t0 + lr) * NIDX + h * 64 + cseg * 16;
        const float* krow = QIW + (size_t)(s0 + lr) * NIDX + 256 + cseg * 16;
#pragma unroll
        for (int q4 = 0; q4 < 4; ++q4) {
            int d = cseg * 16 + q4 * 4;
            float4 v = *(const float4*)(qrow + q4 * 4);
            qit[d + 0][lr] = v.x; qit[d + 1][lr] = v.y;
            qit[d + 2][lr] = v.z; qit[d + 3][lr] = v.w;
            if (h == 0) {
                float4 u = *(const float4*)(krow + q4 * 4);
                kit[d + 0][lr] = u.x; kit[d + 1][lr] = u.y;
                kit[d + 2][lr] = u.z; kit[d + 3][lr] = u.w;
            }
        }
        __syncthreads();
        float dot[4][4] = {};
#pragma unroll 8
        for (int d = 0; d < 64; ++d) {
            float4 a4 = *(const float4*)&qit[d][ty * 4];
            float4 b4 = *(const float4*)&kit[d][tx * 4];
            float av[4] = { a4.x, a4.y, a4.z, a4.w };
            float bv[4] = { b4.x, b4.y, b4.z, b4.w };
#pragma unroll
            for (int i = 0; i < 4; ++i)
#pragma unroll
                for (int j = 0; j < 4; ++j)
                    dot[i][j] += av[i] * bv[j];
        }
#pragma unroll
        for (int i = 0; i < 4; ++i) {
            float w = wis[ty * 4 + i][h];
#pragma unroll
            for (int j = 0; j < 4; ++j)
                acc[i][j] += w * fmaxf(dot[i][j], 0.f);
        }
    }
#pragma unroll
    for (int i = 0; i < 4; ++i) {
        float4 o4 = { acc[i][0], acc[i][1], acc[i][2], acc[i][3] };
        *(float4*)&scores[(size_t)(t0 + ty * 4 + i) * S_LEN + s0 + tx * 4] = o4;
    }
}

// ---------------- Top-K via radix select (exact lax.top_k set semantics) ----------------
__global__ __launch_bounds__(256) void topk_kernel(const float* __restrict__ scores,
    int* __restrict__ topidx, int* __restrict__ topcnt)
{
    int t = blockIdx.x, tid = threadIdx.x;
    int n = t + 1;
    if (n <= TOPK) {
        if (tid < n) topidx[t * TOPK + tid] = tid;
        if (tid == 0) topcnt[t] = n;
        return;
    }
    __shared__ unsigned sc[S_LEN];
    __shared__ unsigned hist[256];
    __shared__ int selbin_s;
    __shared__ int cnt_out;
    __shared__ unsigned wsum[4];
    for (int j = tid; j < n; j += 256) {
        unsigned u = __builtin_bit_cast(unsigned, scores[(size_t)t * S_LEN + j]);
        sc[j] = (u & 0x80000000u) ? ~u : (u | 0x80000000u);
    }
    if (tid == 0) cnt_out = 0;
    int lane = tid & 63, wv = tid >> 6;
    unsigned prefix = 0;
    int kk = TOPK;
#pragma unroll
    for (int round = 0; round < 4; ++round) {
        int shift_pref = 32 - 8 * round;
        int shift_bin = 24 - 8 * round;
        hist[tid] = 0;
        __syncthreads();
        for (int j = tid; j < n; j += 256) {
            unsigned v = sc[j];
            if ((((unsigned long long)(v ^ prefix)) >> shift_pref) == 0)
                atomicAdd(&hist[(v >> shift_bin) & 0xff], 1u);
        }
        __syncthreads();
        if (wv == 0) {
            unsigned h0 = hist[4 * lane], h1 = hist[4 * lane + 1];
            unsigned h2 = hist[4 * lane + 2], h3 = hist[4 * lane + 3];
            unsigned s3 = h3, s2 = h2 + s3, s1 = h1 + s2, s0 = h0 + s1;
            unsigned acc = s0;
            for (int off = 1; off < 64; off <<= 1) {
                unsigned o = __shfl_down(acc, off);
                if (lane + off < 64) acc += o;
            }
            unsigned above = acc - s0;
            hist[4 * lane]     = s0 + above;
            hist[4 * lane + 1] = s1 + above;
            hist[4 * lane + 2] = s2 + above;
            hist[4 * lane + 3] = s3 + above;
        }
        __syncthreads();
        {
            unsigned sufb = hist[tid];
            unsigned sufn = (tid < 255) ? hist[tid + 1] : 0u;
            if (sufb >= (unsigned)kk && sufn < (unsigned)kk)
                selbin_s = tid;
        }
        __syncthreads();
        int b = selbin_s;
        unsigned above = (b < 255) ? hist[b + 1] : 0u;
        kk -= (int)above;
        prefix |= ((unsigned)b) << shift_bin;
        __syncthreads();
    }
    unsigned T = prefix;
    int chunk = (n + 255) >> 8;
    int jb = tid * chunk;
    int je = jb + chunk; if (je > n) je = n;
    int ties = 0;
    for (int j = jb; j < je; ++j) {
        unsigned v = sc[j];
        if (v > T) { int o = atomicAdd(&cnt_out, 1); topidx[t * TOPK + o] = j; }
        else if (v == T) ++ties;
    }
    unsigned inc = (unsigned)ties;
    for (int off = 1; off < 64; off <<= 1) {
        unsigned o = __shfl_up(inc, off);
        if (lane >= off) inc += o;
    }
    if (lane == 63) wsum[wv] = inc;
    __syncthreads();
    unsigned woff = 0;
    for (int w = 0; w < wv; ++w) woff += wsum[w];
    int rank = (int)(woff + inc) - ties;
    for (int j = jb; j < je && rank < kk; ++j) {
        if (sc[j] == T) {
            int o = atomicAdd(&cnt_out, 1);
            topidx[t * TOPK + o] = j;
            ++rank;
        }
    }
    if (tid == 0) topcnt[t] = TOPK;
}

// ---------------- Sparse SDPA v4: one head per wave, grid (S, 4) ----------------
__global__ __launch_bounds__(256) void attn_kernel(
    const unsigned short* __restrict__ Qb, const unsigned short* __restrict__ Kb,
    const unsigned short* __restrict__ Vb,
    const int* __restrict__ topidx, const int* __restrict__ topcnt,
    unsigned short* __restrict__ out)
{
    int t = blockIdx.x, tid = threadIdx.x;
    __shared__ int sel[TOPK];
    if (tid < TOPK) sel[tid] = topidx[t * TOPK + tid];
    __syncthreads();
    int cnt = topcnt[t];
    int lane = tid & 63, wv = tid >> 6;
    int h = blockIdx.y * 4 + wv;
    int klo = lane >> 3, oct = lane & 7;
    int rows[8];
    bool valid[8];
#pragma unroll
    for (int kg = 0; kg < 8; ++kg) {
        int k = kg * 8 + klo;
        valid[kg] = (k < cnt);
        rows[kg] = sel[valid[kg] ? k : 0];
    }
    bf16x8 q8 = *(const bf16x8*)(Qb + (size_t)t * D_MODEL + h * HDIM + oct * 8);
    float qf[8];
#pragma unroll
    for (int e = 0; e < 8; ++e) qf[e] = bf2f((unsigned short)q8[e]);

    const unsigned short* kbase = Kb + (size_t)h * S_LEN * HDIM + oct * 8;
    float p[8];
#pragma unroll
    for (int kg = 0; kg < 8; ++kg) {
        bf16x8 k8 = *(const bf16x8*)(kbase + (size_t)rows[kg] * HDIM);
        float d = 0.f;
#pragma unroll
        for (int e = 0; e < 8; ++e)
            d += bf2f((unsigned short)k8[e]) * qf[e];
        d += __shfl_xor(d, 1);
        d += __shfl_xor(d, 2);
        d += __shfl_xor(d, 4);
        p[kg] = valid[kg] ? d * 0.125f : -INFINITY;
    }
    float m = p[0];
#pragma unroll
    for (int kg = 1; kg < 8; ++kg) m = fmaxf(m, p[kg]);
    m = fmaxf(m, __shfl_xor(m, 8));
    m = fmaxf(m, __shfl_xor(m, 16));
    m = fmaxf(m, __shfl_xor(m, 32));
    float sum = 0.f;
#pragma unroll
    for (int kg = 0; kg < 8; ++kg) { p[kg] = __expf(p[kg] - m); sum += p[kg]; }
    sum += __shfl_xor(sum, 8);
    sum += __shfl_xor(sum, 16);
    sum += __shfl_xor(sum, 32);
    float rs = 1.f / sum;
    const unsigned short* vbase = Vb + (size_t)h * S_LEN * HDIM + oct * 8;
    float facc[8] = {};
#pragma unroll
    for (int kg = 0; kg < 8; ++kg) {
        bf16x8 v8 = *(const bf16x8*)(vbase + (size_t)rows[kg] * HDIM);
        float pw = p[kg] * rs;
#pragma unroll
        for (int e = 0; e < 8; ++e)
            facc[e] += pw * bf2f((unsigned short)v8[e]);
    }
#pragma unroll
    for (int e = 0; e < 8; ++e) {
        facc[e] += __shfl_xor(facc[e], 8);
        facc[e] += __shfl_xor(facc[e], 16);
        facc[e] += __shfl_xor(facc[e], 32);
    }
    if (klo == 0) {
        ushort4 o0 = { f2bf(facc[0]), f2bf(facc[1]), f2bf(facc[2]), f2bf(facc[3]) };
        ushort4 o1 = { f2bf(facc[4]), f2bf(facc[5]), f2bf(facc[6]), f2bf(facc[7]) };
        *(ushort4*)(out + (size_t)t * D_MODEL + h * HDIM + oct * 8) = o0;
        *(ushort4*)(out + (size_t)t * D_MODEL + h * HDIM + oct * 8 + 4) = o1;
    }
}

extern "C" void kernel_launch(void* const* d_in, const int* in_sizes, int n_in,
                              void* d_out, int out_size, void* d_ws, size_t ws_size,
                              hipStream_t stream)
{
    const float* x      = (const float*)d_in[0];
    const float* w_qkv  = (const float*)d_in[1];
    const float* w_o    = (const float*)d_in[2];
    const float* ffn_w1 = (const float*)d_in[3];
    const float* ffn_b1 = (const float*)d_in[4];
    const float* ffn_w2 = (const float*)d_in[5];
    const float* ffn_b2 = (const float*)d_in[6];
    const float* ln1_g  = (const float*)d_in[7];
    const float* ln1_b  = (const float*)d_in[8];
    const float* ln2_g  = (const float*)d_in[9];
    const float* ln2_b  = (const float*)d_in[10];
    const float* idx_wq = (const float*)d_in[11];
    const float* idx_wk = (const float*)d_in[12];
    const float* idx_ww = (const float*)d_in[13];
    float* outp = (float*)d_out;

    const size_t MB = 1ull << 20;
    char* ws = (char*)d_ws;
    float*          normx    = (float*)(ws + 0);
    unsigned short* attno_bf = (unsigned short*)(ws + 0);
    float*          Pf2      = (float*)(ws + 0);
    unsigned short* normx_bf = (unsigned short*)(ws + 8 * MB);
    unsigned short* h2_bf    = normx_bf;
    int*            topidx   = (int*)(ws + 12 * MB);
    int*            topcnt   = (int*)(ws + 12 * MB + 512 * 1024);
    unsigned short* wqkv_t   = (unsigned short*)(ws + 24 * MB);
    unsigned short* wo_t     = (unsigned short*)(ws + 30 * MB);
    unsigned short* w1_t     = (unsigned short*)(ws + 32 * MB);
    unsigned short* w2_t     = (unsigned short*)(ws + 40 * MB);
    unsigned short* Qb       = (unsigned short*)(ws + 48 * MB);
    unsigned short* Kb       = (unsigned short*)(ws + 52 * MB);
    unsigned short* Vb       = (unsigned short*)(ws + 56 * MB);
    float*          ctab     = (float*)(ws + 60 * MB);
    float*          stab     = (float*)(ws + 60 * MB + 256 * 1024);
    float*          P_idx    = (float*)(ws + 61 * MB);
    float*          scoresb  = (float*)(ws + 60 * MB);
    float*          Pwo      = (float*)(ws + 60 * MB);
    unsigned short* ffn1_bf  = (unsigned short*)(ws + 60 * MB);
    float*          QIW      = (float*)(ws + 76 * MB);
    float*          Wc       = (float*)(ws + 79 * MB);

    dim3 blk256(256);
    auto g64n = [](int N, int M) { return dim3(N / 64, M / 128); };

    // 1. fused prep: LN1 + rope tables + 4x weight transpose + indexer weight pack
    prep_kernel<<<PREP_TOTAL, blk256, 0, stream>>>(x, ln1_g, ln1_b,
        w_qkv, w_o, ffn_w1, ffn_w2, idx_wq, idx_wk, idx_ww,
        normx, normx_bf, wqkv_t, wo_t, w1_t, w2_t, Wc, ctab, stab);
    // 2. qkv GEMM + fused RoPE/pack -> Qb, Kb, Vb (768 blocks)
    gemm_qkv_rope<<<g64n(3 * D_MODEL, S_LEN), blk256, 0, stream>>>(normx_bf, wqkv_t,
        ctab, stab, Qb, Kb, Vb);
    // 3. indexer projections (fp32, split-K=4 -> 768 blocks)
    gemm64<<<dim3((NIDX + 63) / 64, S_LEN / 64, 4), blk256, 0, stream>>>(normx, Wc,
        nullptr, S_LEN, NIDX, D_MODEL, P_idx, D_MODEL / 4);
    // 4. reduce indexer partials -> QIW
    kreduce_kernel<<<1024, blk256, 0, stream>>>(P_idx, 4, QIW, nullptr, nullptr, S_LEN, NIDX);
    // 5. indexer scores (overwrites dead ctab/P_idx region)
    scores_kernel<<<dim3(32, 32), blk256, 0, stream>>>(QIW, scoresb);
    // 6. top-64 per row (radix select)
    topk_kernel<<<S_LEN, blk256, 0, stream>>>(scoresb, topidx, topcnt);
    // 7. sparse attention -> bf16 (one head per wave; overlays dead normx)
    attn_kernel<<<dim3(S_LEN, 4), blk256, 0, stream>>>(Qb, Kb, Vb, topidx, topcnt, attno_bf);
    // 8. x1 partials = attn_out @ w_o — split-K=2 (512 blocks, n64 A-in-reg) into Pwo
    gemm_bf16_n64<<<dim3(D_MODEL / 64, S_LEN / 128, 2), blk256, 0, stream>>>(attno_bf, wo_t,
        nullptr, nullptr, nullptr, nullptr, S_LEN, D_MODEL, D_MODEL, 0, Pwo, D_MODEL / 2);
    // 9. fused: x1 = Pwo0+Pwo1+x -> outp; h = LN2(x1) -> bf16
    wo_ln2_kernel<<<S_LEN, blk256, 0, stream>>>(Pwo, x, ln2_g, ln2_b, outp, h2_bf);
    // 10. ffn1 = gelu(h @ w1 + b1) -> bf16 (n64 A-in-reg; 1024 blocks)
    gemm_bf16_n64<<<g64n(DFF, S_LEN), blk256, 0, stream>>>(h2_bf, w1_t,
        nullptr, ffn1_bf, ffn_b1, nullptr, S_LEN, DFF, D_MODEL, 1, nullptr, D_MODEL);
    // 11. out = x1 + ffn1 @ w2 + b2 — n64 A-in-reg split-K=4 (1024 blocks), then reduce
    gemm_bf16_n64<<<dim3(D_MODEL / 64, S_LEN / 128, 4), blk256, 0, stream>>>(ffn1_bf, w2_t,
        nullptr, nullptr, nullptr, nullptr, S_LEN, D_MODEL, DFF, 0, Pf2, DFF / 4);
    kreduce_kernel<<<1024, blk256, 0, stream>>>(Pf2, 4, outp, ffn_b2, outp, S_LEN, D_MODEL);
}

// Round 19
// 256.470 us; speedup vs baseline: 1.0597x; 1.0597x over previous
//
#include <hip/hip_runtime.h>
#include <math.h>

#define S_LEN 2048
#define D_MODEL 1024
#define NHEAD 16
#define HDIM 64
#define DFF 4096
#define IH 4
#define IDM 64
#define TOPK 64
#define NIDX 336   // 256 qi + 64 ki + 4 wi + 12 pad

typedef float f32x4 __attribute__((ext_vector_type(4)));
typedef short bf16x8 __attribute__((ext_vector_type(8)));

__device__ __forceinline__ unsigned short f2bf(float f) {
    unsigned u = __builtin_bit_cast(unsigned, f);
    u += 0x7fff + ((u >> 16) & 1);
    return (unsigned short)(u >> 16);
}
__device__ __forceinline__ float bf2f(unsigned short us) {
    return __builtin_bit_cast(float, (unsigned)us << 16);
}

__device__ __forceinline__ float gelu_exact(float v) {
    return 0.5f * v * (1.f + erff(v * 0.70710678118654752f));
}

__device__ __forceinline__ void gl_lds16(const void* g, void* l) {
    __builtin_amdgcn_global_load_lds(
        (const __attribute__((address_space(1))) void*)g,
        (__attribute__((address_space(3))) void*)l, 16, 0, 0);
}

// ---------------- Fused w_o split-K reduce + residual + LN2 ----------------
__global__ __launch_bounds__(256) void wo_ln2_kernel(const float* __restrict__ Pwo,
    const float* __restrict__ x, const float* __restrict__ g, const float* __restrict__ b,
    float* __restrict__ outf, unsigned short* __restrict__ outb)
{
    int row = blockIdx.x, tid = threadIdx.x;
    size_t MN = (size_t)S_LEN * D_MODEL;
    size_t off = (size_t)row * D_MODEL + tid * 4;
    float4 p0 = *(const float4*)(Pwo + off);
    float4 p1 = *(const float4*)(Pwo + MN + off);
    float4 xr = *(const float4*)(x + off);
    float4 v;
    v.x = p0.x + p1.x + xr.x;
    v.y = p0.y + p1.y + xr.y;
    v.z = p0.z + p1.z + xr.z;
    v.w = p0.w + p1.w + xr.w;
    *(float4*)(outf + off) = v;
    float s = v.x + v.y + v.z + v.w;
    float ss = v.x * v.x + v.y * v.y + v.z * v.z + v.w * v.w;
    int lane = tid & 63, wv = tid >> 6;
    for (int o = 32; o; o >>= 1) { s += __shfl_xor(s, o); ss += __shfl_xor(ss, o); }
    __shared__ float rs[4], rss[4];
    if (lane == 0) { rs[wv] = s; rss[wv] = ss; }
    __syncthreads();
    float S = rs[0] + rs[1] + rs[2] + rs[3];
    float SS = rss[0] + rss[1] + rss[2] + rss[3];
    float mean = S * (1.f / D_MODEL);
    float var = SS * (1.f / D_MODEL) - mean * mean;
    float r = rsqrtf(var + 1e-5f);
    float4 gv = *(const float4*)(g + tid * 4);
    float4 bv = *(const float4*)(b + tid * 4);
    ushort4 u4 = { f2bf((v.x - mean) * r * gv.x + bv.x),
                   f2bf((v.y - mean) * r * gv.y + bv.y),
                   f2bf((v.z - mean) * r * gv.z + bv.z),
                   f2bf((v.w - mean) * r * gv.w + bv.w) };
    *(ushort4*)(outb + off) = u4;
}

// ---------------- wtrans body: fp32 [K][N] -> bf16 [N][K], one 32x32 tile ----------------
__device__ __forceinline__ void wtrans_body(const float* __restrict__ in,
    unsigned short* __restrict__ out, int K, int N, int bx, int by, int tid)
{
    __shared__ float t[32][33];
    int k0 = by * 32, n0 = bx * 32;
    int r = tid >> 5, c = tid & 31;
#pragma unroll
    for (int p = 0; p < 4; ++p)
        t[r + p * 8][c] = in[(size_t)(k0 + r + p * 8) * N + n0 + c];
    __syncthreads();
#pragma unroll
    for (int p = 0; p < 4; ++p)
        out[(size_t)(n0 + r + p * 8) * K + k0 + c] = f2bf(t[c][r + p * 8]);
}

// ---------------- Fused prep: LN1 + rope tables + 4x weight transpose + indexer pack ----------------
#define PREP_LN1    2048
#define PREP_ROPE   256
#define PREP_WQKV   3072
#define PREP_WO     1024
#define PREP_W1     4096
#define PREP_W2     4096
#define PREP_WPACK  1344
#define PREP_TOTAL  (PREP_LN1 + PREP_ROPE + PREP_WQKV + PREP_WO + PREP_W1 + PREP_W2 + PREP_WPACK)
__global__ __launch_bounds__(256) void prep_kernel(
    const float* __restrict__ x, const float* __restrict__ ln1_g, const float* __restrict__ ln1_b,
    const float* __restrict__ w_qkv, const float* __restrict__ w_o,
    const float* __restrict__ w1, const float* __restrict__ w2,
    const float* __restrict__ wq, const float* __restrict__ wk, const float* __restrict__ ww,
    float* __restrict__ normx, unsigned short* __restrict__ normx_bf,
    unsigned short* __restrict__ wqkv_t, unsigned short* __restrict__ wo_t,
    unsigned short* __restrict__ w1_t, unsigned short* __restrict__ w2_t,
    float* __restrict__ Wc, float* __restrict__ ct, float* __restrict__ st)
{
    int b = blockIdx.x, tid = threadIdx.x;
    if (b < PREP_LN1) {
        int row = b;
        const float4 v = *(const float4*)(x + (size_t)row * D_MODEL + tid * 4);
        float s = v.x + v.y + v.z + v.w;
        float ss = v.x * v.x + v.y * v.y + v.z * v.z + v.w * v.w;
        int lane = tid & 63, wv = tid >> 6;
        for (int o = 32; o; o >>= 1) { s += __shfl_xor(s, o); ss += __shfl_xor(ss, o); }
        __shared__ float rs[4], rss[4];
        if (lane == 0) { rs[wv] = s; rss[wv] = ss; }
        __syncthreads();
        float S = rs[0] + rs[1] + rs[2] + rs[3];
        float SS = rss[0] + rss[1] + rss[2] + rss[3];
        float mean = S * (1.f / D_MODEL);
        float var = SS * (1.f / D_MODEL) - mean * mean;
        float r = rsqrtf(var + 1e-5f);
        float4 gv = *(const float4*)(ln1_g + tid * 4);
        float4 bv = *(const float4*)(ln1_b + tid * 4);
        float4 o4;
        o4.x = (v.x - mean) * r * gv.x + bv.x;
        o4.y = (v.y - mean) * r * gv.y + bv.y;
        o4.z = (v.z - mean) * r * gv.z + bv.z;
        o4.w = (v.w - mean) * r * gv.w + bv.w;
        *(float4*)(normx + (size_t)row * D_MODEL + tid * 4) = o4;
        ushort4 u4 = { f2bf(o4.x), f2bf(o4.y), f2bf(o4.z), f2bf(o4.w) };
        *(ushort4*)(normx_bf + (size_t)row * D_MODEL + tid * 4) = u4;
        return;
    }
    b -= PREP_LN1;
    if (b < PREP_ROPE) {
        int g = b * 256 + tid;
        int t = g >> 5, i = g & 31;
        float theta = powf(10000.f, -(float)i / 32.f);
        float ang = (float)t * theta;
        ct[g] = cosf(ang);
        st[g] = sinf(ang);
        return;
    }
    b -= PREP_ROPE;
    if (b < PREP_WQKV) { wtrans_body(w_qkv, wqkv_t, 1024, 3072, b % 96, b / 96, tid); return; }
    b -= PREP_WQKV;
    if (b < PREP_WO)   { wtrans_body(w_o, wo_t, 1024, 1024, b % 32, b / 32, tid); return; }
    b -= PREP_WO;
    if (b < PREP_W1)   { wtrans_body(w1, w1_t, 1024, 4096, b % 128, b / 128, tid); return; }
    b -= PREP_W1;
    if (b < PREP_W2)   { wtrans_body(w2, w2_t, 4096, 1024, b % 32, b / 32, tid); return; }
    b -= PREP_W2;
    {
        int idx = b * 256 + tid;
        if (idx >= D_MODEL * NIDX) return;
        int r = idx / NIDX, c = idx % NIDX;
        float v = 0.f;
        if (c < 256) v = wq[r * 256 + c];
        else if (c < 320) v = wk[r * 64 + (c - 256)];
        else if (c < 324) v = ww[r * 4 + (c - 320)];
        Wc[idx] = v;
    }
}

// ---------------- bf16 MFMA GEMM, 128x64 tile, 3-deep pipeline w/ counted vmcnt ----------------
__global__ __launch_bounds__(256) void gemm_bf16_n64(
    const unsigned short* __restrict__ A, const unsigned short* __restrict__ Bt,
    float* __restrict__ C, unsigned short* __restrict__ Cb,
    const float* __restrict__ bias, const float* __restrict__ R,
    int M, int N, int K, int act,
    float* __restrict__ P, int kchunk)
{
    __shared__ __attribute__((aligned(16))) unsigned short As[3][128 * 32];
    __shared__ __attribute__((aligned(16))) unsigned short Bs[3][64 * 32];
    int tid = threadIdx.x;
    int bm = blockIdx.y * 128, bn = blockIdx.x * 64;
    int wid = tid >> 6, lane = tid & 63;
    int wm = wid * 32;
    const unsigned short* Ab = A + (size_t)bm * K;
    const unsigned short* Bb = Bt + (size_t)bn * K;
    f32x4 acc[2][4];
#pragma unroll
    for (int i = 0; i < 2; ++i)
#pragma unroll
        for (int j = 0; j < 4; ++j)
            acc[i][j] = (f32x4){0.f, 0.f, 0.f, 0.f};

    int kbeg = blockIdx.z * kchunk;
    int NT = kchunk >> 5;
    int fr = lane & 15, fk = (lane >> 4) * 8;
    int e0 = tid * 8;
    int r0 = e0 >> 5, c0 = e0 & 31;

    auto STAGE = [&](int kt, int buf) {
        int k0 = kbeg + kt * 32;
        gl_lds16(Ab + (size_t)r0 * K + k0 + c0, &As[buf][e0]);
        gl_lds16(Ab + (size_t)(r0 + 64) * K + k0 + c0, &As[buf][e0 + 2048]);
        gl_lds16(Bb + (size_t)r0 * K + k0 + c0, &Bs[buf][e0]);
    };
    auto COMPUTE = [&](int buf) {
        bf16x8 af[2], bfv[4];
#pragma unroll
        for (int mi = 0; mi < 2; ++mi)
            af[mi] = *(const bf16x8*)&As[buf][(wm + mi * 16 + fr) * 32 + fk];
#pragma unroll
        for (int ni = 0; ni < 4; ++ni)
            bfv[ni] = *(const bf16x8*)&Bs[buf][(ni * 16 + fr) * 32 + fk];
#pragma unroll
        for (int mi = 0; mi < 2; ++mi)
#pragma unroll
            for (int ni = 0; ni < 4; ++ni)
                acc[mi][ni] = __builtin_amdgcn_mfma_f32_16x16x32_bf16(
                    af[mi], bfv[ni], acc[mi][ni], 0, 0, 0);
    };

    STAGE(0, 0);
    STAGE(1, 1);
    asm volatile("s_waitcnt vmcnt(3)" ::: "memory");
    __builtin_amdgcn_s_barrier();

    for (int kt = 0; kt < NT - 2; ++kt) {
        STAGE(kt + 2, (kt + 2) % 3);
        COMPUTE(kt % 3);
        asm volatile("s_waitcnt vmcnt(3)" ::: "memory");
        __builtin_amdgcn_s_barrier();
    }
    COMPUTE((NT - 2) % 3);
    asm volatile("s_waitcnt vmcnt(0)" ::: "memory");
    __builtin_amdgcn_s_barrier();
    COMPUTE((NT - 1) % 3);

    int cl = lane & 15, rh = (lane >> 4) * 4;
    if (P) {
        float* Pz = P + (size_t)blockIdx.z * M * N;
#pragma unroll
        for (int mi = 0; mi < 2; ++mi)
#pragma unroll
            for (int ni = 0; ni < 4; ++ni) {
                int col = bn + ni * 16 + cl;
#pragma unroll
                for (int r = 0; r < 4; ++r) {
                    int row = bm + wm + mi * 16 + rh + r;
                    Pz[(size_t)row * N + col] = acc[mi][ni][r];
                }
            }
        return;
    }
#pragma unroll
    for (int mi = 0; mi < 2; ++mi) {
#pragma unroll
        for (int ni = 0; ni < 4; ++ni) {
            int col = bn + ni * 16 + cl;
            float bv = bias ? bias[col] : 0.f;
#pragma unroll
            for (int r = 0; r < 4; ++r) {
                int row = bm + wm + mi * 16 + rh + r;
                float v = acc[mi][ni][r] + bv;
                if (act) v = gelu_exact(v);
                size_t off = (size_t)row * N + col;
                if (R) v += R[off];
                if (C) C[off] = v;
                if (Cb) Cb[off] = f2bf(v);
            }
        }
    }
}

// ---------------- qkv GEMM + fused RoPE + pack: writes Qb [S][1024], Kb/Vb [H][S][64] ----------------
__global__ __launch_bounds__(256) void gemm_qkv_rope(
    const unsigned short* __restrict__ A, const unsigned short* __restrict__ Bt,
    const float* __restrict__ ct, const float* __restrict__ st,
    unsigned short* __restrict__ Qb, unsigned short* __restrict__ Kb,
    unsigned short* __restrict__ Vb)
{
    const int K = D_MODEL, NT = D_MODEL / 32;
    __shared__ __attribute__((aligned(16))) unsigned short As[3][128 * 32];
    __shared__ __attribute__((aligned(16))) unsigned short Bs[3][64 * 32];
    int tid = threadIdx.x;
    int bm = blockIdx.y * 128, bn = blockIdx.x * 64;
    int wid = tid >> 6, lane = tid & 63;
    int wm = wid * 32;
    const unsigned short* Ab = A + (size_t)bm * K;
    const unsigned short* Bb = Bt + (size_t)bn * K;
    f32x4 acc[2][4];
#pragma unroll
    for (int i = 0; i < 2; ++i)
#pragma unroll
        for (int j = 0; j < 4; ++j)
            acc[i][j] = (f32x4){0.f, 0.f, 0.f, 0.f};

    int fr = lane & 15, fk = (lane >> 4) * 8;
    int e0 = tid * 8;
    int r0 = e0 >> 5, c0 = e0 & 31;

    auto STAGE = [&](int kt, int buf) {
        int k0 = kt * 32;
        gl_lds16(Ab + (size_t)r0 * K + k0 + c0, &As[buf][e0]);
        gl_lds16(Ab + (size_t)(r0 + 64) * K + k0 + c0, &As[buf][e0 + 2048]);
        gl_lds16(Bb + (size_t)r0 * K + k0 + c0, &Bs[buf][e0]);
    };
    auto COMPUTE = [&](int buf) {
        bf16x8 af[2], bfv[4];
#pragma unroll
        for (int mi = 0; mi < 2; ++mi)
            af[mi] = *(const bf16x8*)&As[buf][(wm + mi * 16 + fr) * 32 + fk];
#pragma unroll
        for (int ni = 0; ni < 4; ++ni)
            bfv[ni] = *(const bf16x8*)&Bs[buf][(ni * 16 + fr) * 32 + fk];
#pragma unroll
        for (int mi = 0; mi < 2; ++mi)
#pragma unroll
            for (int ni = 0; ni < 4; ++ni)
                acc[mi][ni] = __builtin_amdgcn_mfma_f32_16x16x32_bf16(
                    af[mi], bfv[ni], acc[mi][ni], 0, 0, 0);
    };

    STAGE(0, 0);
    STAGE(1, 1);
    asm volatile("s_waitcnt vmcnt(3)" ::: "memory");
    __builtin_amdgcn_s_barrier();
    for (int kt = 0; kt < NT - 2; ++kt) {
        STAGE(kt + 2, (kt + 2) % 3);
        COMPUTE(kt % 3);
        asm volatile("s_waitcnt vmcnt(3)" ::: "memory");
        __builtin_amdgcn_s_barrier();
    }
    COMPUTE((NT - 2) % 3);
    asm volatile("s_waitcnt vmcnt(0)" ::: "memory");
    __builtin_amdgcn_s_barrier();
    COMPUTE((NT - 1) % 3);

    int cl = lane & 15, rh = (lane >> 4) * 4;
    int region = bn >> 10;            // 0=Q, 1=K, 2=V
    int hh = (bn & 1023) >> 6;        // head
    if (region == 2) {
#pragma unroll
        for (int mi = 0; mi < 2; ++mi)
#pragma unroll
            for (int ni = 0; ni < 4; ++ni) {
                int d = ni * 16 + cl;
#pragma unroll
                for (int r = 0; r < 4; ++r) {
                    int row = bm + wm + mi * 16 + rh + r;
                    Vb[((size_t)hh * S_LEN + row) * HDIM + d] = f2bf(acc[mi][ni][r]);
                }
            }
    } else {
#pragma unroll
        for (int mi = 0; mi < 2; ++mi)
#pragma unroll
            for (int ni = 0; ni < 4; ++ni) {
                int d = ni * 16 + cl;
                int i = d >> 1;
                bool odd = d & 1;
#pragma unroll
                for (int r = 0; r < 4; ++r) {
                    int row = bm + wm + mi * 16 + rh + r;
                    float v = acc[mi][ni][r];
                    float p = __shfl_xor(v, 1);
                    float c = ct[row * 32 + i], s = st[row * 32 + i];
                    float o = odd ? (v * c + p * s) : (v * c - p * s);
                    if (region == 0)
                        Qb[(size_t)row * D_MODEL + bn + d] = f2bf(o);
                    else
                        Kb[((size_t)hh * S_LEN + row) * HDIM + d] = f2bf(o);
                }
            }
    }
}

// ---------------- Split-K reduce: C = sum_z P[z] + bias + R (float4 vectorized) ----------------
__global__ __launch_bounds__(256) void kreduce_kernel(const float* __restrict__ P,
    int nslice, float* __restrict__ C, const float* __restrict__ bias,
    const float* __restrict__ R, int M, int N)
{
    size_t total4 = (size_t)M * N / 4;
    size_t stride = (size_t)gridDim.x * 256;
    for (size_t i4 = blockIdx.x * 256 + threadIdx.x; i4 < total4; i4 += stride) {
        size_t off = i4 * 4;
        float4 v = *(const float4*)(P + off);
        for (int z = 1; z < nslice; ++z) {
            float4 p = *(const float4*)(P + (size_t)z * M * N + off);
            v.x += p.x; v.y += p.y; v.z += p.z; v.w += p.w;
        }
        if (bias) {
            float4 b4 = *(const float4*)(bias + (off % N));
            v.x += b4.x; v.y += b4.y; v.z += b4.z; v.w += b4.w;
        }
        if (R) {
            float4 r4 = *(const float4*)(R + off);
            v.x += r4.x; v.y += r4.y; v.z += r4.z; v.w += r4.w;
        }
        *(float4*)(C + off) = v;
    }
}

// ---------------- Generic fp32 GEMM (indexer path): C[M,N] = A[M,K]@B[K,N] ----------------
__global__ __launch_bounds__(256) void gemm64(const float* __restrict__ A,
    const float* __restrict__ B, float* __restrict__ C,
    int M, int N, int K,
    float* __restrict__ P, int kchunk)
{
    __shared__ float As[16][68];
    __shared__ float Bs[16][68];
    int tid = threadIdx.x;
    int bm = blockIdx.y, bn = blockIdx.x;
    int tx = tid & 15, ty = tid >> 4;
    int arow = tid >> 2;
    int acol = (tid & 3) << 2;
    int brow = tid >> 4;
    int bcol = (tid & 15) << 2;
    const float* Abase = A + (size_t)(bm * 64 + arow) * K + acol;
    float c[4][4] = {};
    int kbeg = blockIdx.z * kchunk;
    int kend = kbeg + kchunk;
    for (int k0 = kbeg; k0 < kend; k0 += 16) {
        float4 av = *(const float4*)(Abase + k0);
        As[acol + 0][arow] = av.x;
        As[acol + 1][arow] = av.y;
        As[acol + 2][arow] = av.z;
        As[acol + 3][arow] = av.w;
        int gcol = bn * 64 + bcol;
        const float* Bb = B + (size_t)(k0 + brow) * N;
        float4 bv;
        if (gcol + 3 < N) {
            bv = *(const float4*)(Bb + gcol);
        } else {
            bv.x = (gcol + 0 < N) ? Bb[gcol + 0] : 0.f;
            bv.y = (gcol + 1 < N) ? Bb[gcol + 1] : 0.f;
            bv.z = (gcol + 2 < N) ? Bb[gcol + 2] : 0.f;
            bv.w = (gcol + 3 < N) ? Bb[gcol + 3] : 0.f;
        }
        *(float4*)&Bs[brow][bcol] = bv;
        __syncthreads();
#pragma unroll
        for (int kk = 0; kk < 16; ++kk) {
            float4 a4 = *(const float4*)&As[kk][ty * 4];
            float4 b4 = *(const float4*)&Bs[kk][tx * 4];
            float av4[4] = { a4.x, a4.y, a4.z, a4.w };
            float bv4[4] = { b4.x, b4.y, b4.z, b4.w };
#pragma unroll
            for (int i = 0; i < 4; ++i)
#pragma unroll
                for (int j = 0; j < 4; ++j)
                    c[i][j] += av4[i] * bv4[j];
        }
        __syncthreads();
    }
    float* Out = P ? (P + (size_t)blockIdx.z * M * N) : C;
#pragma unroll
    for (int i = 0; i < 4; ++i) {
        int row = bm * 64 + ty * 4 + i;
#pragma unroll
        for (int j = 0; j < 4; ++j) {
            int col = bn * 64 + tx * 4 + j;
            if (col < N)
                Out[(size_t)row * N + col] = c[i][j];
        }
    }
}

// ---------------- Indexer scores v2: 64x64 tile, d-major LDS, 4x4 register blocking ----------------
__global__ __launch_bounds__(256) void scores_kernel(const float* __restrict__ QIW,
    float* __restrict__ scores)
{
    int t0 = blockIdx.y * 64, s0 = blockIdx.x * 64;
    if (s0 > t0 + 63) return;
    __shared__ float qit[64][68];   // [d][t]
    __shared__ float kit[64][68];   // [d][s]
    __shared__ float wis[64][4];
    int tid = threadIdx.x;
    int tx = tid & 15, ty = tid >> 4;
    int lr = tid & 63;
    int cseg = tid >> 6;
    if (tid < 64) {
        float4 w4 = *(const float4*)(QIW + (size_t)(t0 + tid) * NIDX + 320);
        wis[tid][0] = w4.x; wis[tid][1] = w4.y; wis[tid][2] = w4.z; wis[tid][3] = w4.w;
    }
    float acc[4][4] = {};
#pragma unroll
    for (int h = 0; h < 4; ++h) {
        __syncthreads();
        const float* qrow = QIW + (size_t)(t0 + lr) * NIDX + h * 64 + cseg * 16;
        const float* krow = QIW + (size_t)(s0 + lr) * NIDX + 256 + cseg * 16;
#pragma unroll
        for (int q4 = 0; q4 < 4; ++q4) {
            int d = cseg * 16 + q4 * 4;
            float4 v = *(const float4*)(qrow + q4 * 4);
            qit[d + 0][lr] = v.x; qit[d + 1][lr] = v.y;
            qit[d + 2][lr] = v.z; qit[d + 3][lr] = v.w;
            if (h == 0) {
                float4 u = *(const float4*)(krow + q4 * 4);
                kit[d + 0][lr] = u.x; kit[d + 1][lr] = u.y;
                kit[d + 2][lr] = u.z; kit[d + 3][lr] = u.w;
            }
        }
        __syncthreads();
        float dot[4][4] = {};
#pragma unroll 8
        for (int d = 0; d < 64; ++d) {
            float4 a4 = *(const float4*)&qit[d][ty * 4];
            float4 b4 = *(const float4*)&kit[d][tx * 4];
            float av[4] = { a4.x, a4.y, a4.z, a4.w };
            float bv[4] = { b4.x, b4.y, b4.z, b4.w };
#pragma unroll
            for (int i = 0; i < 4; ++i)
#pragma unroll
                for (int j = 0; j < 4; ++j)
                    dot[i][j] += av[i] * bv[j];
        }
#pragma unroll
        for (int i = 0; i < 4; ++i) {
            float w = wis[ty * 4 + i][h];
#pragma unroll
            for (int j = 0; j < 4; ++j)
                acc[i][j] += w * fmaxf(dot[i][j], 0.f);
        }
    }
#pragma unroll
    for (int i = 0; i < 4; ++i) {
        float4 o4 = { acc[i][0], acc[i][1], acc[i][2], acc[i][3] };
        *(float4*)&scores[(size_t)(t0 + ty * 4 + i) * S_LEN + s0 + tx * 4] = o4;
    }
}

// ---------------- Top-K via radix select (exact lax.top_k set semantics) ----------------
__global__ __launch_bounds__(256) void topk_kernel(const float* __restrict__ scores,
    int* __restrict__ topidx, int* __restrict__ topcnt)
{
    int t = blockIdx.x, tid = threadIdx.x;
    int n = t + 1;
    if (n <= TOPK) {
        if (tid < n) topidx[t * TOPK + tid] = tid;
        if (tid == 0) topcnt[t] = n;
        return;
    }
    __shared__ unsigned sc[S_LEN];
    __shared__ unsigned hist[256];
    __shared__ int selbin_s;
    __shared__ int cnt_out;
    __shared__ unsigned wsum[4];
    for (int j = tid; j < n; j += 256) {
        unsigned u = __builtin_bit_cast(unsigned, scores[(size_t)t * S_LEN + j]);
        sc[j] = (u & 0x80000000u) ? ~u : (u | 0x80000000u);
    }
    if (tid == 0) cnt_out = 0;
    int lane = tid & 63, wv = tid >> 6;
    unsigned prefix = 0;
    int kk = TOPK;
#pragma unroll
    for (int round = 0; round < 4; ++round) {
        int shift_pref = 32 - 8 * round;
        int shift_bin = 24 - 8 * round;
        hist[tid] = 0;
        __syncthreads();
        for (int j = tid; j < n; j += 256) {
            unsigned v = sc[j];
            if ((((unsigned long long)(v ^ prefix)) >> shift_pref) == 0)
                atomicAdd(&hist[(v >> shift_bin) & 0xff], 1u);
        }
        __syncthreads();
        if (wv == 0) {
            unsigned h0 = hist[4 * lane], h1 = hist[4 * lane + 1];
            unsigned h2 = hist[4 * lane + 2], h3 = hist[4 * lane + 3];
            unsigned s3 = h3, s2 = h2 + s3, s1 = h1 + s2, s0 = h0 + s1;
            unsigned acc = s0;
            for (int off = 1; off < 64; off <<= 1) {
                unsigned o = __shfl_down(acc, off);
                if (lane + off < 64) acc += o;
            }
            unsigned above = acc - s0;
            hist[4 * lane]     = s0 + above;
            hist[4 * lane + 1] = s1 + above;
            hist[4 * lane + 2] = s2 + above;
            hist[4 * lane + 3] = s3 + above;
        }
        __syncthreads();
        {
            unsigned sufb = hist[tid];
            unsigned sufn = (tid < 255) ? hist[tid + 1] : 0u;
            if (sufb >= (unsigned)kk && sufn < (unsigned)kk)
                selbin_s = tid;
        }
        __syncthreads();
        int b = selbin_s;
        unsigned above = (b < 255) ? hist[b + 1] : 0u;
        kk -= (int)above;
        prefix |= ((unsigned)b) << shift_bin;
        __syncthreads();
    }
    unsigned T = prefix;
    int chunk = (n + 255) >> 8;
    int jb = tid * chunk;
    int je = jb + chunk; if (je > n) je = n;
    int ties = 0;
    for (int j = jb; j < je; ++j) {
        unsigned v = sc[j];
        if (v > T) { int o = atomicAdd(&cnt_out, 1); topidx[t * TOPK + o] = j; }
        else if (v == T) ++ties;
    }
    unsigned inc = (unsigned)ties;
    for (int off = 1; off < 64; off <<= 1) {
        unsigned o = __shfl_up(inc, off);
        if (lane >= off) inc += o;
    }
    if (lane == 63) wsum[wv] = inc;
    __syncthreads();
    unsigned woff = 0;
    for (int w = 0; w < wv; ++w) woff += wsum[w];
    int rank = (int)(woff + inc) - ties;
    for (int j = jb; j < je && rank < kk; ++j) {
        if (sc[j] == T) {
            int o = atomicAdd(&cnt_out, 1);
            topidx[t * TOPK + o] = j;
            ++rank;
        }
    }
    if (tid == 0) topcnt[t] = TOPK;
}

// ---------------- Sparse SDPA v4: one head per wave, grid (S, 4) ----------------
__global__ __launch_bounds__(256) void attn_kernel(
    const unsigned short* __restrict__ Qb, const unsigned short* __restrict__ Kb,
    const unsigned short* __restrict__ Vb,
    const int* __restrict__ topidx, const int* __restrict__ topcnt,
    unsigned short* __restrict__ out)
{
    int t = blockIdx.x, tid = threadIdx.x;
    __shared__ int sel[TOPK];
    if (tid < TOPK) sel[tid] = topidx[t * TOPK + tid];
    __syncthreads();
    int cnt = topcnt[t];
    int lane = tid & 63, wv = tid >> 6;
    int h = blockIdx.y * 4 + wv;
    int klo = lane >> 3, oct = lane & 7;
    int rows[8];
    bool valid[8];
#pragma unroll
    for (int kg = 0; kg < 8; ++kg) {
        int k = kg * 8 + klo;
        valid[kg] = (k < cnt);
        rows[kg] = sel[valid[kg] ? k : 0];
    }
    bf16x8 q8 = *(const bf16x8*)(Qb + (size_t)t * D_MODEL + h * HDIM + oct * 8);
    float qf[8];
#pragma unroll
    for (int e = 0; e < 8; ++e) qf[e] = bf2f((unsigned short)q8[e]);

    const unsigned short* kbase = Kb + (size_t)h * S_LEN * HDIM + oct * 8;
    float p[8];
#pragma unroll
    for (int kg = 0; kg < 8; ++kg) {
        bf16x8 k8 = *(const bf16x8*)(kbase + (size_t)rows[kg] * HDIM);
        float d = 0.f;
#pragma unroll
        for (int e = 0; e < 8; ++e)
            d += bf2f((unsigned short)k8[e]) * qf[e];
        d += __shfl_xor(d, 1);
        d += __shfl_xor(d, 2);
        d += __shfl_xor(d, 4);
        p[kg] = valid[kg] ? d * 0.125f : -INFINITY;
    }
    float m = p[0];
#pragma unroll
    for (int kg = 1; kg < 8; ++kg) m = fmaxf(m, p[kg]);
    m = fmaxf(m, __shfl_xor(m, 8));
    m = fmaxf(m, __shfl_xor(m, 16));
    m = fmaxf(m, __shfl_xor(m, 32));
    float sum = 0.f;
#pragma unroll
    for (int kg = 0; kg < 8; ++kg) { p[kg] = __expf(p[kg] - m); sum += p[kg]; }
    sum += __shfl_xor(sum, 8);
    sum += __shfl_xor(sum, 16);
    sum += __shfl_xor(sum, 32);
    float rs = 1.f / sum;
    const unsigned short* vbase = Vb + (size_t)h * S_LEN * HDIM + oct * 8;
    float facc[8] = {};
#pragma unroll
    for (int kg = 0; kg < 8; ++kg) {
        bf16x8 v8 = *(const bf16x8*)(vbase + (size_t)rows[kg] * HDIM);
        float pw = p[kg] * rs;
#pragma unroll
        for (int e = 0; e < 8; ++e)
            facc[e] += pw * bf2f((unsigned short)v8[e]);
    }
#pragma unroll
    for (int e = 0; e < 8; ++e) {
        facc[e] += __shfl_xor(facc[e], 8);
        facc[e] += __shfl_xor(facc[e], 16);
        facc[e] += __shfl_xor(facc[e], 32);
    }
    if (klo == 0) {
        ushort4 o0 = { f2bf(facc[0]), f2bf(facc[1]), f2bf(facc[2]), f2bf(facc[3]) };
        ushort4 o1 = { f2bf(facc[4]), f2bf(facc[5]), f2bf(facc[6]), f2bf(facc[7]) };
        *(ushort4*)(out + (size_t)t * D_MODEL + h * HDIM + oct * 8) = o0;
        *(ushort4*)(out + (size_t)t * D_MODEL + h * HDIM + oct * 8 + 4) = o1;
    }
}

extern "C" void kernel_launch(void* const* d_in, const int* in_sizes, int n_in,
                              void* d_out, int out_size, void* d_ws, size_t ws_size,
                              hipStream_t stream)
{
    const float* x      = (const float*)d_in[0];
    const float* w_qkv  = (const float*)d_in[1];
    const float* w_o    = (const float*)d_in[2];
    const float* ffn_w1 = (const float*)d_in[3];
    const float* ffn_b1 = (const float*)d_in[4];
    const float* ffn_w2 = (const float*)d_in[5];
    const float* ffn_b2 = (const float*)d_in[6];
    const float* ln1_g  = (const float*)d_in[7];
    const float* ln1_b  = (const float*)d_in[8];
    const float* ln2_g  = (const float*)d_in[9];
    const float* ln2_b  = (const float*)d_in[10];
    const float* idx_wq = (const float*)d_in[11];
    const float* idx_wk = (const float*)d_in[12];
    const float* idx_ww = (const float*)d_in[13];
    float* outp = (float*)d_out;

    const size_t MB = 1ull << 20;
    char* ws = (char*)d_ws;
    float*          normx    = (float*)(ws + 0);
    unsigned short* attno_bf = (unsigned short*)(ws + 0);
    float*          Pf2      = (float*)(ws + 0);
    unsigned short* normx_bf = (unsigned short*)(ws + 8 * MB);
    unsigned short* h2_bf    = normx_bf;
    int*            topidx   = (int*)(ws + 12 * MB);
    int*            topcnt   = (int*)(ws + 12 * MB + 512 * 1024);
    unsigned short* wqkv_t   = (unsigned short*)(ws + 24 * MB);
    unsigned short* wo_t     = (unsigned short*)(ws + 30 * MB);
    unsigned short* w1_t     = (unsigned short*)(ws + 32 * MB);
    unsigned short* w2_t     = (unsigned short*)(ws + 40 * MB);
    unsigned short* Qb       = (unsigned short*)(ws + 48 * MB);
    unsigned short* Kb       = (unsigned short*)(ws + 52 * MB);
    unsigned short* Vb       = (unsigned short*)(ws + 56 * MB);
    float*          ctab     = (float*)(ws + 60 * MB);
    float*          stab     = (float*)(ws + 60 * MB + 256 * 1024);
    float*          P_idx    = (float*)(ws + 61 * MB);
    float*          scoresb  = (float*)(ws + 60 * MB);
    float*          Pwo      = (float*)(ws + 60 * MB);
    unsigned short* ffn1_bf  = (unsigned short*)(ws + 60 * MB);
    float*          QIW      = (float*)(ws + 76 * MB);
    float*          Wc       = (float*)(ws + 79 * MB);

    dim3 blk256(256);
    auto g64n = [](int N, int M) { return dim3(N / 64, M / 128); };

    // 1. fused prep: LN1 + rope tables + 4x weight transpose + indexer weight pack
    prep_kernel<<<PREP_TOTAL, blk256, 0, stream>>>(x, ln1_g, ln1_b,
        w_qkv, w_o, ffn_w1, ffn_w2, idx_wq, idx_wk, idx_ww,
        normx, normx_bf, wqkv_t, wo_t, w1_t, w2_t, Wc, ctab, stab);
    // 2. qkv GEMM + fused RoPE/pack -> Qb, Kb, Vb (768 blocks)
    gemm_qkv_rope<<<g64n(3 * D_MODEL, S_LEN), blk256, 0, stream>>>(normx_bf, wqkv_t,
        ctab, stab, Qb, Kb, Vb);
    // 3. indexer projections (fp32, split-K=4 -> 768 blocks)
    gemm64<<<dim3((NIDX + 63) / 64, S_LEN / 64, 4), blk256, 0, stream>>>(normx, Wc,
        nullptr, S_LEN, NIDX, D_MODEL, P_idx, D_MODEL / 4);
    // 4. reduce indexer partials -> QIW
    kreduce_kernel<<<1024, blk256, 0, stream>>>(P_idx, 4, QIW, nullptr, nullptr, S_LEN, NIDX);
    // 5. indexer scores (overwrites dead ctab/P_idx region)
    scores_kernel<<<dim3(32, 32), blk256, 0, stream>>>(QIW, scoresb);
    // 6. top-64 per row (radix select)
    topk_kernel<<<S_LEN, blk256, 0, stream>>>(scoresb, topidx, topcnt);
    // 7. sparse attention -> bf16 (one head per wave; overlays dead normx)
    attn_kernel<<<dim3(S_LEN, 4), blk256, 0, stream>>>(Qb, Kb, Vb, topidx, topcnt, attno_bf);
    // 8. x1 partials = attn_out @ w_o — split-K=2 (512 blocks, n64) into Pwo
    gemm_bf16_n64<<<dim3(D_MODEL / 64, S_LEN / 128, 2), blk256, 0, stream>>>(attno_bf, wo_t,
        nullptr, nullptr, nullptr, nullptr, S_LEN, D_MODEL, D_MODEL, 0, Pwo, D_MODEL / 2);
    // 9. fused: x1 = Pwo0+Pwo1+x -> outp; h = LN2(x1) -> bf16
    wo_ln2_kernel<<<S_LEN, blk256, 0, stream>>>(Pwo, x, ln2_g, ln2_b, outp, h2_bf);
    // 10. ffn1 = gelu(h @ w1 + b1) -> bf16 (n64 tile; 1024 blocks)
    gemm_bf16_n64<<<g64n(DFF, S_LEN), blk256, 0, stream>>>(h2_bf, w1_t,
        nullptr, ffn1_bf, ffn_b1, nullptr, S_LEN, DFF, D_MODEL, 1, nullptr, D_MODEL);
    // 11. out = x1 + ffn1 @ w2 + b2 — n64 split-K=4 (1024 blocks) into Pf2, then reduce
    gemm_bf16_n64<<<dim3(D_MODEL / 64, S_LEN / 128, 4), blk256, 0, stream>>>(ffn1_bf, w2_t,
        nullptr, nullptr, nullptr, nullptr, S_LEN, D_MODEL, DFF, 0, Pf2, DFF / 4);
    kreduce_kernel<<<1024, blk256, 0, stream>>>(Pf2, 4, outp, ffn_b2, outp, S_LEN, D_MODEL);
}